// Round 14
// baseline (118.410 us; speedup 1.0000x reference)
//
#include <hip/hip_runtime.h>

typedef unsigned char u8;
typedef unsigned short u16;
typedef unsigned int u32;
typedef __attribute__((ext_vector_type(8))) short short8;   // bf16x8 MFMA frag
typedef __attribute__((ext_vector_type(4))) float f32x4;    // MFMA acc frag
typedef __attribute__((ext_vector_type(4))) u32 u32x4;      // 16B record

// Problem constants (match reference)
constexpr int NODES = 100000;
constexpr int EDGES = 800000;
constexpr int DIM = 128;       // node dim
constexpr int EDIM = 8;        // edge attr dim
constexpr int HEADS = 8;

__device__ inline u16 f2bf(float f) {              // f32 -> bf16 RNE
    u32 u = __float_as_uint(f);
    u = (u + 0x7FFFu + ((u >> 16) & 1u)) >> 16;
    return (u16)u;
}
__device__ inline float bf2f(u16 s) {              // bf16 -> f32 exact
    return __uint_as_float(((u32)s) << 16);
}

// ---------------------------------------------------------------------------
// node_proj via MFMA (R4-proven core + direct-store epilogue — the R13
// LDS-transpose epilogue was measured 3.6us WORSE and is reverted).
// Fused head4 init to -1 (2 coalesced ints/thread) + sentinel recE[-1];
// stream order makes both visible to build_rec / aggregate.
// ---------------------------------------------------------------------------
__global__ __launch_bounds__(256) void node_proj_mfma(const float* __restrict__ x,
                                                      const float* __restrict__ Wn,
                                                      const float* __restrict__ bn,
                                                      u16* __restrict__ xpb,
                                                      int* __restrict__ head4,
                                                      u32x4* __restrict__ recE) {
    __shared__ u16 sW[128 * 136];   // 34816 B, +8 pad per row

    const int tid = threadIdx.x;

    if (head4 != nullptr) {   // init head4: NODES*4 ints, 2 per thread
        int t = blockIdx.x * 256 + tid;
        if (t < NODES * 2) {
            head4[2 * t] = -1;
            head4[2 * t + 1] = -1;
        }
        if (blockIdx.x == 0 && tid == 0)
            recE[-1] = u32x4{(u32)-1, 0u, 0u, 0u};   // sentinel self-loop
    }

    {   // stage W: f32 global -> bf16 LDS, 128 rows x 16 chunks of 8
        #pragma unroll
        for (int i = tid; i < 128 * 16; i += 256) {
            int row = i >> 4, ch = i & 15;
            const float* p = Wn + row * DIM + ch * 8;
            float4 f0 = *reinterpret_cast<const float4*>(p);
            float4 f1 = *reinterpret_cast<const float4*>(p + 4);
            short8 v;
            v[0]=(short)f2bf(f0.x); v[1]=(short)f2bf(f0.y);
            v[2]=(short)f2bf(f0.z); v[3]=(short)f2bf(f0.w);
            v[4]=(short)f2bf(f1.x); v[5]=(short)f2bf(f1.y);
            v[6]=(short)f2bf(f1.z); v[7]=(short)f2bf(f1.w);
            *reinterpret_cast<short8*>(&sW[row * 136 + ch * 8]) = v;
        }
    }
    __syncthreads();

    const int w = tid >> 6;        // wave 0..3
    const int l = tid & 63;
    const int lr = l & 15;
    const int lh = l >> 4;
    const int m0 = blockIdx.x * 128 + w * 32;

    f32x4 acc[2][8];
    #pragma unroll
    for (int mt = 0; mt < 2; ++mt)
        #pragma unroll
        for (int nt = 0; nt < 8; ++nt) acc[mt][nt] = f32x4{0, 0, 0, 0};

    #pragma unroll
    for (int kk = 0; kk < 4; ++kk) {
        const int kb = kk * 32 + lh * 8;
        short8 a0, a1;
        {
            int row = m0 + lr;  row = row < NODES ? row : 0;
            const float* p = x + (size_t)row * DIM + kb;
            float4 f0 = *reinterpret_cast<const float4*>(p);
            float4 f1 = *reinterpret_cast<const float4*>(p + 4);
            a0[0]=(short)f2bf(f0.x); a0[1]=(short)f2bf(f0.y);
            a0[2]=(short)f2bf(f0.z); a0[3]=(short)f2bf(f0.w);
            a0[4]=(short)f2bf(f1.x); a0[5]=(short)f2bf(f1.y);
            a0[6]=(short)f2bf(f1.z); a0[7]=(short)f2bf(f1.w);
        }
        {
            int row = m0 + 16 + lr;  row = row < NODES ? row : 0;
            const float* p = x + (size_t)row * DIM + kb;
            float4 f0 = *reinterpret_cast<const float4*>(p);
            float4 f1 = *reinterpret_cast<const float4*>(p + 4);
            a1[0]=(short)f2bf(f0.x); a1[1]=(short)f2bf(f0.y);
            a1[2]=(short)f2bf(f0.z); a1[3]=(short)f2bf(f0.w);
            a1[4]=(short)f2bf(f1.x); a1[5]=(short)f2bf(f1.y);
            a1[6]=(short)f2bf(f1.z); a1[7]=(short)f2bf(f1.w);
        }
        #pragma unroll
        for (int nt = 0; nt < 8; ++nt) {
            short8 b = *reinterpret_cast<const short8*>(&sW[(nt * 16 + lr) * 136 + kb]);
            acc[0][nt] = __builtin_amdgcn_mfma_f32_16x16x32_bf16(a0, b, acc[0][nt], 0, 0, 0);
            acc[1][nt] = __builtin_amdgcn_mfma_f32_16x16x32_bf16(a1, b, acc[1][nt], 0, 0, 0);
        }
    }

    float bias[8];
    #pragma unroll
    for (int nt = 0; nt < 8; ++nt) bias[nt] = bn[nt * 16 + lr];

    #pragma unroll
    for (int mt = 0; mt < 2; ++mt) {
        #pragma unroll
        for (int r = 0; r < 4; ++r) {
            int grow = m0 + mt * 16 + lh * 4 + r;
            if (grow < NODES) {
                #pragma unroll
                for (int nt = 0; nt < 8; ++nt)
                    xpb[(size_t)grow * DIM + nt * 16 + lr] =
                        f2bf(acc[mt][nt][r] + bias[nt]);
            }
        }
    }
}

// ---------------------------------------------------------------------------
// build_rec (288B LDS -> full occupancy): link-build + gates. 16B record:
//   [0,4): next (-1 = end)  [4,8): src*DIM (elem offset)  [8,16): 8 gates u8
// 4-way split lists: head4[tgt*4 + (e&3)]. Only head4 takes random atomics.
// ---------------------------------------------------------------------------
__global__ __launch_bounds__(256) void build_rec(const int* __restrict__ ei,
                                                 const float* __restrict__ ea,
                                                 const float* __restrict__ We,
                                                 const float* __restrict__ be,
                                                 int* __restrict__ head4,
                                                 u32x4* __restrict__ recE) {
    __shared__ float sW[HEADS * EDIM];
    __shared__ float sb[HEADS];
    if (threadIdx.x < HEADS * EDIM) sW[threadIdx.x] = We[threadIdx.x];
    if (threadIdx.x < HEADS) sb[threadIdx.x] = be[threadIdx.x];
    __syncthreads();

    const int e = blockIdx.x * 256 + threadIdx.x;
    if (e >= EDGES) return;

    const int src = ei[e];
    const int tgt = ei[EDGES + e];
    float4 a0 = *reinterpret_cast<const float4*>(ea + (size_t)e * EDIM);
    float4 a1 = *reinterpret_cast<const float4*>(ea + (size_t)e * EDIM + 4);

    u32 q[HEADS];
    #pragma unroll
    for (int h = 0; h < HEADS; ++h) {
        const float* w = &sW[h * EDIM];
        float z = sb[h]
                + a0.x * w[0] + a0.y * w[1] + a0.z * w[2] + a0.w * w[3]
                + a1.x * w[4] + a1.y * w[5] + a1.z * w[6] + a1.w * w[7];
        float g = 1.0f / (1.0f + __expf(-z));
        q[h] = (u32)(g * 255.0f + 0.5f);
    }

    int nx = atomicExch(&head4[tgt * 4 + (e & 3)], e);   // -1 tail OK

    u32x4 r;
    r[0] = (u32)nx;
    r[1] = (u32)(src * DIM);      // pre-scaled element offset
    r[2] = q[0] | (q[1] << 8) | (q[2] << 16) | (q[3] << 24);
    r[3] = q[4] | (q[5] << 8) | (q[6] << 16) | (q[7] << 24);
    recE[e] = r;                  // coalesced 16B
}

// ---------------------------------------------------------------------------
// aggregate_v11: 16-lane group per node, 4 chains, sentinel-based branchless
// walk (proven v10 shape). NEW: nontemporal record loads — records are
// read-exactly-once (12.8MB); nt keeps them from evicting the 8x-reused xpb
// rows from L2/L3. Regular out stores (R9: nt-stores inflate WRITE_SIZE).
// ---------------------------------------------------------------------------
__global__ __launch_bounds__(256) void aggregate_v11(const u16* __restrict__ xpb,
                                                     const int* __restrict__ head4,
                                                     const u32x4* __restrict__ recE,
                                                     float* __restrict__ out) {
    const int n = blockIdx.x * 16 + (threadIdx.x >> 4);
    if (n >= NODES) return;
    const int l = threadIdx.x & 15;    // lane in group
    const int h = l >> 1;              // head for this lane's 8 cols
    const int hsh = (h & 3) * 8;       // byte shift within gate word
    const bool hlo = (h < 4);

    float acc[8];
    #pragma unroll
    for (int i = 0; i < 8; ++i) acc[i] = 0.0f;

    int e0 = head4[n * 4 + 0];
    int e1 = head4[n * 4 + 1];
    int e2 = head4[n * 4 + 2];
    int e3 = head4[n * 4 + 3];

    while ((e0 & e1 & e2 & e3) != -1) {
        u32x4 R0 = __builtin_nontemporal_load(recE + (ptrdiff_t)e0);  // -1 -> sentinel
        u32x4 R1 = __builtin_nontemporal_load(recE + (ptrdiff_t)e1);
        u32x4 R2 = __builtin_nontemporal_load(recE + (ptrdiff_t)e2);
        u32x4 R3 = __builtin_nontemporal_load(recE + (ptrdiff_t)e3);
        float g0 = (float)(((hlo ? R0[2] : R0[3]) >> hsh) & 0xFF);
        float g1 = (float)(((hlo ? R1[2] : R1[3]) >> hsh) & 0xFF);
        float g2 = (float)(((hlo ? R2[2] : R2[3]) >> hsh) & 0xFF);
        float g3 = (float)(((hlo ? R3[2] : R3[3]) >> hsh) & 0xFF);
        short8 u0 = *reinterpret_cast<const short8*>(xpb + R0[1] + l * 8);
        short8 u1 = *reinterpret_cast<const short8*>(xpb + R1[1] + l * 8);
        short8 u2 = *reinterpret_cast<const short8*>(xpb + R2[1] + l * 8);
        short8 u3 = *reinterpret_cast<const short8*>(xpb + R3[1] + l * 8);
        #pragma unroll
        for (int i = 0; i < 8; ++i) {
            acc[i] += g0 * bf2f((u16)u0[i]);
            acc[i] += g1 * bf2f((u16)u1[i]);
            acc[i] += g2 * bf2f((u16)u2[i]);
            acc[i] += g3 * bf2f((u16)u3[i]);
        }
        e0 = (int)R0[0];
        e1 = (int)R1[0];
        e2 = (int)R2[0];
        e3 = (int)R3[0];
    }

    constexpr float DQ = 1.0f / 255.0f;
    float4 o0 = {acc[0] * DQ, acc[1] * DQ, acc[2] * DQ, acc[3] * DQ};
    float4 o1 = {acc[4] * DQ, acc[5] * DQ, acc[6] * DQ, acc[7] * DQ};
    float4* op = reinterpret_cast<float4*>(out + (size_t)n * DIM + l * 8);
    op[0] = o0;
    op[1] = o1;
}

// ---------------------------------------------------------------------------
// Fallback (small ws): per-edge atomic scatter reading bf16 xp
// ---------------------------------------------------------------------------
__global__ __launch_bounds__(256) void edge_scatter(const int* __restrict__ ei,
                                                    const float* __restrict__ ea,
                                                    const float* __restrict__ We,
                                                    const float* __restrict__ be,
                                                    const u16* __restrict__ xpb,
                                                    float* __restrict__ out) {
    __shared__ float sW[HEADS * EDIM];
    __shared__ float sb[HEADS];
    if (threadIdx.x < HEADS * EDIM) sW[threadIdx.x] = We[threadIdx.x];
    if (threadIdx.x < HEADS) sb[threadIdx.x] = be[threadIdx.x];
    __syncthreads();

    const int t = blockIdx.x * 256 + threadIdx.x;
    const int e = t >> 5;
    const int l = t & 31;
    if (e >= EDGES) return;

    const int src = ei[e];
    const int tgt = ei[EDGES + e];
    const int h = l >> 2;

    float4 ea0 = *reinterpret_cast<const float4*>(ea + (size_t)e * EDIM);
    float4 ea1 = *reinterpret_cast<const float4*>(ea + (size_t)e * EDIM + 4);
    float4 wa = *reinterpret_cast<const float4*>(&sW[h * EDIM]);
    float4 wb = *reinterpret_cast<const float4*>(&sW[h * EDIM + 4]);
    float z = sb[h]
            + ea0.x * wa.x + ea0.y * wa.y + ea0.z * wa.z + ea0.w * wa.w
            + ea1.x * wb.x + ea1.y * wb.y + ea1.z * wb.z + ea1.w * wb.w;
    float g = 1.0f / (1.0f + __expf(-z));

    ushort4 u = *reinterpret_cast<const ushort4*>(xpb + (size_t)src * DIM + l * 4);
    float* op = out + (size_t)tgt * DIM + l * 4;
    unsafeAtomicAdd(op + 0, bf2f(u.x) * g);
    unsafeAtomicAdd(op + 1, bf2f(u.y) * g);
    unsafeAtomicAdd(op + 2, bf2f(u.z) * g);
    unsafeAtomicAdd(op + 3, bf2f(u.w) * g);
}

// ---------------------------------------------------------------------------
extern "C" void kernel_launch(void* const* d_in, const int* in_sizes, int n_in,
                              void* d_out, int out_size, void* d_ws, size_t ws_size,
                              hipStream_t stream) {
    const float* x   = (const float*)d_in[0];
    const int*   ei  = (const int*)d_in[1];
    const float* eat = (const float*)d_in[2];
    const float* Wn  = (const float*)d_in[3];
    const float* bn  = (const float*)d_in[4];
    const float* We  = (const float*)d_in[5];
    const float* be  = (const float*)d_in[6];
    float* out = (float*)d_out;

    // workspace layout (all segments 16B-aligned)
    u16* xpb   = (u16*)d_ws;                                // NODES*128 bf16 (25.6MB)
    int* head4 = (int*)(xpb + (size_t)NODES * DIM);         // NODES*4 i32 (1.6MB)
    char* recS = (char*)(head4 + (size_t)NODES * 4);        // (EDGES+1)*16 B
    u32x4* recE = (u32x4*)(recS + 16);                      // recE[-1] = sentinel

    const size_t need = (size_t)NODES * DIM * 2 + (size_t)NODES * 16
                      + (size_t)(EDGES + 1) * 16;           // ~40 MB
    const size_t need_fb = (size_t)NODES * DIM * 2;         // fallback: xpb only

    if (ws_size >= need) {
        node_proj_mfma<<<(NODES + 127) / 128, 256, 0, stream>>>(x, Wn, bn, xpb,
                                                                head4, recE);
        build_rec<<<(EDGES + 255) / 256, 256, 0, stream>>>(ei, eat, We, be,
                                                           head4, recE);
        aggregate_v11<<<(NODES + 15) / 16, 256, 0, stream>>>(xpb, head4, recE, out);
    } else if (ws_size >= need_fb) {
        node_proj_mfma<<<(NODES + 127) / 128, 256, 0, stream>>>(x, Wn, bn, xpb,
                                                                nullptr, nullptr);
        hipMemsetAsync(d_out, 0, (size_t)out_size * sizeof(float), stream);
        edge_scatter<<<(EDGES * 32) / 256, 256, 0, stream>>>(ei, eat, We, be, xpb, out);
    }
}

// Round 15
// 108.589 us; speedup vs baseline: 1.0904x; 1.0904x over previous
//
#include <hip/hip_runtime.h>

typedef unsigned char u8;
typedef unsigned short u16;
typedef unsigned int u32;
typedef __attribute__((ext_vector_type(8))) short short8;   // bf16x8 MFMA frag
typedef __attribute__((ext_vector_type(4))) float f32x4;    // MFMA acc frag
typedef __attribute__((ext_vector_type(4))) u32 u32x4;      // 16B record

// Problem constants (match reference)
constexpr int NODES = 100000;
constexpr int EDGES = 800000;
constexpr int DIM = 128;       // node dim
constexpr int EDIM = 8;        // edge attr dim
constexpr int HEADS = 8;

__device__ inline u16 f2bf(float f) {              // f32 -> bf16 RNE
    u32 u = __float_as_uint(f);
    u = (u + 0x7FFFu + ((u >> 16) & 1u)) >> 16;
    return (u16)u;
}
__device__ inline float bf2f(u16 s) {              // bf16 -> f32 exact
    return __uint_as_float(((u32)s) << 16);
}

// ---------------------------------------------------------------------------
// node_proj via MFMA (R4-proven core + direct-store epilogue).
// Fused head4 init to -1 (2 coalesced ints/thread) + sentinel recE[-1].
// ---------------------------------------------------------------------------
__global__ __launch_bounds__(256) void node_proj_mfma(const float* __restrict__ x,
                                                      const float* __restrict__ Wn,
                                                      const float* __restrict__ bn,
                                                      u16* __restrict__ xpb,
                                                      int* __restrict__ head4,
                                                      u32x4* __restrict__ recE) {
    __shared__ u16 sW[128 * 136];   // 34816 B, +8 pad per row

    const int tid = threadIdx.x;

    if (head4 != nullptr) {   // init head4: NODES*4 ints, 2 per thread
        int t = blockIdx.x * 256 + tid;
        if (t < NODES * 2) {
            head4[2 * t] = -1;
            head4[2 * t + 1] = -1;
        }
        if (blockIdx.x == 0 && tid == 0)
            recE[-1] = u32x4{(u32)-1, 0u, 0u, 0u};   // sentinel self-loop
    }

    {   // stage W: f32 global -> bf16 LDS, 128 rows x 16 chunks of 8
        #pragma unroll
        for (int i = tid; i < 128 * 16; i += 256) {
            int row = i >> 4, ch = i & 15;
            const float* p = Wn + row * DIM + ch * 8;
            float4 f0 = *reinterpret_cast<const float4*>(p);
            float4 f1 = *reinterpret_cast<const float4*>(p + 4);
            short8 v;
            v[0]=(short)f2bf(f0.x); v[1]=(short)f2bf(f0.y);
            v[2]=(short)f2bf(f0.z); v[3]=(short)f2bf(f0.w);
            v[4]=(short)f2bf(f1.x); v[5]=(short)f2bf(f1.y);
            v[6]=(short)f2bf(f1.z); v[7]=(short)f2bf(f1.w);
            *reinterpret_cast<short8*>(&sW[row * 136 + ch * 8]) = v;
        }
    }
    __syncthreads();

    const int w = tid >> 6;        // wave 0..3
    const int l = tid & 63;
    const int lr = l & 15;
    const int lh = l >> 4;
    const int m0 = blockIdx.x * 128 + w * 32;

    f32x4 acc[2][8];
    #pragma unroll
    for (int mt = 0; mt < 2; ++mt)
        #pragma unroll
        for (int nt = 0; nt < 8; ++nt) acc[mt][nt] = f32x4{0, 0, 0, 0};

    #pragma unroll
    for (int kk = 0; kk < 4; ++kk) {
        const int kb = kk * 32 + lh * 8;
        short8 a0, a1;
        {
            int row = m0 + lr;  row = row < NODES ? row : 0;
            const float* p = x + (size_t)row * DIM + kb;
            float4 f0 = *reinterpret_cast<const float4*>(p);
            float4 f1 = *reinterpret_cast<const float4*>(p + 4);
            a0[0]=(short)f2bf(f0.x); a0[1]=(short)f2bf(f0.y);
            a0[2]=(short)f2bf(f0.z); a0[3]=(short)f2bf(f0.w);
            a0[4]=(short)f2bf(f1.x); a0[5]=(short)f2bf(f1.y);
            a0[6]=(short)f2bf(f1.z); a0[7]=(short)f2bf(f1.w);
        }
        {
            int row = m0 + 16 + lr;  row = row < NODES ? row : 0;
            const float* p = x + (size_t)row * DIM + kb;
            float4 f0 = *reinterpret_cast<const float4*>(p);
            float4 f1 = *reinterpret_cast<const float4*>(p + 4);
            a1[0]=(short)f2bf(f0.x); a1[1]=(short)f2bf(f0.y);
            a1[2]=(short)f2bf(f0.z); a1[3]=(short)f2bf(f0.w);
            a1[4]=(short)f2bf(f1.x); a1[5]=(short)f2bf(f1.y);
            a1[6]=(short)f2bf(f1.z); a1[7]=(short)f2bf(f1.w);
        }
        #pragma unroll
        for (int nt = 0; nt < 8; ++nt) {
            short8 b = *reinterpret_cast<const short8*>(&sW[(nt * 16 + lr) * 136 + kb]);
            acc[0][nt] = __builtin_amdgcn_mfma_f32_16x16x32_bf16(a0, b, acc[0][nt], 0, 0, 0);
            acc[1][nt] = __builtin_amdgcn_mfma_f32_16x16x32_bf16(a1, b, acc[1][nt], 0, 0, 0);
        }
    }

    float bias[8];
    #pragma unroll
    for (int nt = 0; nt < 8; ++nt) bias[nt] = bn[nt * 16 + lr];

    #pragma unroll
    for (int mt = 0; mt < 2; ++mt) {
        #pragma unroll
        for (int r = 0; r < 4; ++r) {
            int grow = m0 + mt * 16 + lh * 4 + r;
            if (grow < NODES) {
                #pragma unroll
                for (int nt = 0; nt < 8; ++nt)
                    xpb[(size_t)grow * DIM + nt * 16 + lr] =
                        f2bf(acc[mt][nt][r] + bias[nt]);
            }
        }
    }
}

// ---------------------------------------------------------------------------
// build_rec (288B LDS -> full occupancy): link-build + gates. 16B record:
//   [0,4): next (-1 = end)  [4,8): src*DIM (elem offset)  [8,16): 8 gates u8
// 4-way split lists: head4[tgt*4 + (e&3)]. Only head4 takes random atomics.
// ---------------------------------------------------------------------------
__global__ __launch_bounds__(256) void build_rec(const int* __restrict__ ei,
                                                 const float* __restrict__ ea,
                                                 const float* __restrict__ We,
                                                 const float* __restrict__ be,
                                                 int* __restrict__ head4,
                                                 u32x4* __restrict__ recE) {
    __shared__ float sW[HEADS * EDIM];
    __shared__ float sb[HEADS];
    if (threadIdx.x < HEADS * EDIM) sW[threadIdx.x] = We[threadIdx.x];
    if (threadIdx.x < HEADS) sb[threadIdx.x] = be[threadIdx.x];
    __syncthreads();

    const int e = blockIdx.x * 256 + threadIdx.x;
    if (e >= EDGES) return;

    const int src = ei[e];
    const int tgt = ei[EDGES + e];
    float4 a0 = *reinterpret_cast<const float4*>(ea + (size_t)e * EDIM);
    float4 a1 = *reinterpret_cast<const float4*>(ea + (size_t)e * EDIM + 4);

    u32 q[HEADS];
    #pragma unroll
    for (int h = 0; h < HEADS; ++h) {
        const float* w = &sW[h * EDIM];
        float z = sb[h]
                + a0.x * w[0] + a0.y * w[1] + a0.z * w[2] + a0.w * w[3]
                + a1.x * w[4] + a1.y * w[5] + a1.z * w[6] + a1.w * w[7];
        float g = 1.0f / (1.0f + __expf(-z));
        q[h] = (u32)(g * 255.0f + 0.5f);
    }

    int nx = atomicExch(&head4[tgt * 4 + (e & 3)], e);   // -1 tail OK

    u32x4 r;
    r[0] = (u32)nx;
    r[1] = (u32)(src * DIM);      // pre-scaled element offset
    r[2] = q[0] | (q[1] << 8) | (q[2] << 16) | (q[3] << 24);
    r[3] = q[4] | (q[5] << 8) | (q[6] << 16) | (q[7] << 24);
    recE[e] = r;                  // coalesced 16B
}

// ---------------------------------------------------------------------------
// aggregate_v10 (best measured: 51.3us): 16-lane group per node, 4 chains,
// sentinel-based branchless walk, REGULAR loads (R14 proved nt-loads cost
// +10us by defeating cache retention on the chain hops).
// ---------------------------------------------------------------------------
__global__ __launch_bounds__(256) void aggregate_v10(const u16* __restrict__ xpb,
                                                     const int* __restrict__ head4,
                                                     const u32x4* __restrict__ recE,
                                                     float* __restrict__ out) {
    const int n = blockIdx.x * 16 + (threadIdx.x >> 4);
    if (n >= NODES) return;
    const int l = threadIdx.x & 15;    // lane in group
    const int h = l >> 1;              // head for this lane's 8 cols
    const int hsh = (h & 3) * 8;       // byte shift within gate word
    const bool hlo = (h < 4);

    float acc[8];
    #pragma unroll
    for (int i = 0; i < 8; ++i) acc[i] = 0.0f;

    int e0 = head4[n * 4 + 0];
    int e1 = head4[n * 4 + 1];
    int e2 = head4[n * 4 + 2];
    int e3 = head4[n * 4 + 3];

    while ((e0 & e1 & e2 & e3) != -1) {
        u32x4 R0 = recE[(ptrdiff_t)e0];    // e=-1 -> sentinel (valid)
        u32x4 R1 = recE[(ptrdiff_t)e1];
        u32x4 R2 = recE[(ptrdiff_t)e2];
        u32x4 R3 = recE[(ptrdiff_t)e3];
        float g0 = (float)(((hlo ? R0[2] : R0[3]) >> hsh) & 0xFF);
        float g1 = (float)(((hlo ? R1[2] : R1[3]) >> hsh) & 0xFF);
        float g2 = (float)(((hlo ? R2[2] : R2[3]) >> hsh) & 0xFF);
        float g3 = (float)(((hlo ? R3[2] : R3[3]) >> hsh) & 0xFF);
        short8 u0 = *reinterpret_cast<const short8*>(xpb + R0[1] + l * 8);
        short8 u1 = *reinterpret_cast<const short8*>(xpb + R1[1] + l * 8);
        short8 u2 = *reinterpret_cast<const short8*>(xpb + R2[1] + l * 8);
        short8 u3 = *reinterpret_cast<const short8*>(xpb + R3[1] + l * 8);
        #pragma unroll
        for (int i = 0; i < 8; ++i) {
            acc[i] += g0 * bf2f((u16)u0[i]);
            acc[i] += g1 * bf2f((u16)u1[i]);
            acc[i] += g2 * bf2f((u16)u2[i]);
            acc[i] += g3 * bf2f((u16)u3[i]);
        }
        e0 = (int)R0[0];
        e1 = (int)R1[0];
        e2 = (int)R2[0];
        e3 = (int)R3[0];
    }

    constexpr float DQ = 1.0f / 255.0f;
    float4 o0 = {acc[0] * DQ, acc[1] * DQ, acc[2] * DQ, acc[3] * DQ};
    float4 o1 = {acc[4] * DQ, acc[5] * DQ, acc[6] * DQ, acc[7] * DQ};
    float4* op = reinterpret_cast<float4*>(out + (size_t)n * DIM + l * 8);
    op[0] = o0;
    op[1] = o1;
}

// ---------------------------------------------------------------------------
// Fallback (small ws): per-edge atomic scatter reading bf16 xp
// ---------------------------------------------------------------------------
__global__ __launch_bounds__(256) void edge_scatter(const int* __restrict__ ei,
                                                    const float* __restrict__ ea,
                                                    const float* __restrict__ We,
                                                    const float* __restrict__ be,
                                                    const u16* __restrict__ xpb,
                                                    float* __restrict__ out) {
    __shared__ float sW[HEADS * EDIM];
    __shared__ float sb[HEADS];
    if (threadIdx.x < HEADS * EDIM) sW[threadIdx.x] = We[threadIdx.x];
    if (threadIdx.x < HEADS) sb[threadIdx.x] = be[threadIdx.x];
    __syncthreads();

    const int t = blockIdx.x * 256 + threadIdx.x;
    const int e = t >> 5;
    const int l = t & 31;
    if (e >= EDGES) return;

    const int src = ei[e];
    const int tgt = ei[EDGES + e];
    const int h = l >> 2;

    float4 ea0 = *reinterpret_cast<const float4*>(ea + (size_t)e * EDIM);
    float4 ea1 = *reinterpret_cast<const float4*>(ea + (size_t)e * EDIM + 4);
    float4 wa = *reinterpret_cast<const float4*>(&sW[h * EDIM]);
    float4 wb = *reinterpret_cast<const float4*>(&sW[h * EDIM + 4]);
    float z = sb[h]
            + ea0.x * wa.x + ea0.y * wa.y + ea0.z * wa.z + ea0.w * wa.w
            + ea1.x * wb.x + ea1.y * wb.y + ea1.z * wb.z + ea1.w * wb.w;
    float g = 1.0f / (1.0f + __expf(-z));

    ushort4 u = *reinterpret_cast<const ushort4*>(xpb + (size_t)src * DIM + l * 4);
    float* op = out + (size_t)tgt * DIM + l * 4;
    unsafeAtomicAdd(op + 0, bf2f(u.x) * g);
    unsafeAtomicAdd(op + 1, bf2f(u.y) * g);
    unsafeAtomicAdd(op + 2, bf2f(u.z) * g);
    unsafeAtomicAdd(op + 3, bf2f(u.w) * g);
}

// ---------------------------------------------------------------------------
extern "C" void kernel_launch(void* const* d_in, const int* in_sizes, int n_in,
                              void* d_out, int out_size, void* d_ws, size_t ws_size,
                              hipStream_t stream) {
    const float* x   = (const float*)d_in[0];
    const int*   ei  = (const int*)d_in[1];
    const float* eat = (const float*)d_in[2];
    const float* Wn  = (const float*)d_in[3];
    const float* bn  = (const float*)d_in[4];
    const float* We  = (const float*)d_in[5];
    const float* be  = (const float*)d_in[6];
    float* out = (float*)d_out;

    // workspace layout (all segments 16B-aligned)
    u16* xpb   = (u16*)d_ws;                                // NODES*128 bf16 (25.6MB)
    int* head4 = (int*)(xpb + (size_t)NODES * DIM);         // NODES*4 i32 (1.6MB)
    char* recS = (char*)(head4 + (size_t)NODES * 4);        // (EDGES+1)*16 B
    u32x4* recE = (u32x4*)(recS + 16);                      // recE[-1] = sentinel

    const size_t need = (size_t)NODES * DIM * 2 + (size_t)NODES * 16
                      + (size_t)(EDGES + 1) * 16;           // ~40 MB
    const size_t need_fb = (size_t)NODES * DIM * 2;         // fallback: xpb only

    if (ws_size >= need) {
        node_proj_mfma<<<(NODES + 127) / 128, 256, 0, stream>>>(x, Wn, bn, xpb,
                                                                head4, recE);
        build_rec<<<(EDGES + 255) / 256, 256, 0, stream>>>(ei, eat, We, be,
                                                           head4, recE);
        aggregate_v10<<<(NODES + 15) / 16, 256, 0, stream>>>(xpb, head4, recE, out);
    } else if (ws_size >= need_fb) {
        node_proj_mfma<<<(NODES + 127) / 128, 256, 0, stream>>>(x, Wn, bn, xpb,
                                                                nullptr, nullptr);
        hipMemsetAsync(d_out, 0, (size_t)out_size * sizeof(float), stream);
        edge_scatter<<<(EDGES * 32) / 256, 256, 0, stream>>>(ei, eat, We, be, xpb, out);
    }
}